// Round 3
// baseline (113.727 us; speedup 1.0000x reference)
//
#include <hip/hip_runtime.h>

// Problem constants (from reference)
#define BB     32
#define C_IN   64
#define HH     64
#define WW     64
#define C_OUT  128
#define CONN   4     // 1 << TREE_DEPTH
// PADDING=2 -> pad_l = pad_r = 1, "edge" mode -> clamp coords to [0, 63]

// Mapping:
//  - one block (256 thr = 4 waves) = one (b, o) output image (64x64)
//  - lane (0..63) = output column j  -> every x load / out store is 64
//    consecutive floats (fully coalesced, 256 B per instruction)
//  - wave w owns rows 16w..16w+15 (i0 wave-uniform -> SALU row addressing)
//  - o block-uniform -> conn/weights/bias scalarize to s_loads
//  - per k: 16 independent loads issued as a batch, then 16 fmax -> high MLP
//  - nontemporal stores: 65 MB output stream must not evict x (2 MB/batch)
//    from the 4 MB/XCD L2
__global__ __launch_bounds__(256) void lp_conv_bt_kernel(
    const float* __restrict__ x,       // (B, C_IN, H, W)
    const float* __restrict__ weights, // (C_OUT, CONN)
    const float* __restrict__ bias,    // (C_OUT)
    const int*   __restrict__ conn,    // (C_OUT, CONN)
    float*       __restrict__ out)     // (B, C_OUT, H, W)
{
    const int bid = blockIdx.x;
    const int b   = bid >> 7;
    const int o   = bid & (C_OUT - 1);

    const int tid  = threadIdx.x;
    const int lane = tid & 63;
    int i0 = (tid >> 6) * 16;
    i0 = __builtin_amdgcn_readfirstlane(i0);   // wave-uniform

    float acc[16];
#pragma unroll
    for (int i = 0; i < 16; ++i) acc[i] = 0.f;

#pragma unroll
    for (int k = 0; k < CONN; ++k) {
        const int   ci = conn[o * CONN + k];   // uniform -> s_load
        const float wk = weights[o * CONN + k];
        int c   = ci / 9;
        int rem = ci - c * 9;
        int di  = rem / 3;
        int dj  = rem - di * 3;

        // per-lane column (the only per-lane VALU for this k)
        int col = lane + dj - 1;
        col = min(max(col, 0), WW - 1);

        const float* base = x + (((size_t)b * C_IN + c) << 12);  // channel base

        float v[16];
#pragma unroll
        for (int i = 0; i < 16; ++i) {
            int hh = i0 + i + di - 1;          // wave-uniform row
            hh = min(max(hh, 0), HH - 1);
            v[i] = base[(hh << 6) + col];      // batch of 16 independent loads
        }
#pragma unroll
        for (int i = 0; i < 16; ++i)
            acc[i] = fmaxf(acc[i], fabsf(wk - v[i]));
    }

    const float bo = bias[o];
    float* po = out + (((size_t)(b * C_OUT + o) * HH + i0) << 6) + lane;
#pragma unroll
    for (int i = 0; i < 16; ++i)
        __builtin_nontemporal_store(acc[i] + bo, po + (i << 6));
}

extern "C" void kernel_launch(void* const* d_in, const int* in_sizes, int n_in,
                              void* d_out, int out_size, void* d_ws, size_t ws_size,
                              hipStream_t stream) {
    const float* x       = (const float*)d_in[0];
    const float* weights = (const float*)d_in[1];
    const float* bias    = (const float*)d_in[2];
    const int*   conn    = (const int*)d_in[3];
    float*       out     = (float*)d_out;

    int grid = BB * C_OUT;   // 4096 blocks of 256 threads
    lp_conv_bt_kernel<<<grid, 256, 0, stream>>>(x, weights, bias, conn, out);
}

// Round 6
// 107.050 us; speedup vs baseline: 1.0624x; 1.0624x over previous
//
#include <hip/hip_runtime.h>

// Problem constants (from reference)
#define BB     32
#define C_IN   64
#define HH     64
#define WW     64
#define C_OUT  128
#define CONN   4     // 1 << TREE_DEPTH
// PADDING=2 -> pad_l = pad_r = 1, "edge" mode -> clamp coords to [0, 63]

// Round-2 structure (proven fastest) + XCD b-locality swizzle.
//  - lane (0..63) = output column j -> fully coalesced 256 B loads/stores
//  - each thread: 8 consecutive rows; block = 4 waves = 32 rows (ihalf picks half)
//  - o block-uniform -> conn/weights/bias scalarize; i0 wave-uniform -> SALU rows
//  - XCD swizzle: hw assigns consecutive blockIdx round-robin to the 8 XCDs
//    (xcd = bid & 7). Map so XCD x serves ONLY batches {4x..4x+3}: x[b] tiles
//    (2 MB each) then live in that XCD's 4 MB L2 across the o-sweep, turning
//    the 268 MB of x re-reads (8x reuse across o, zero within a block) from
//    Infinity-Cache-served into mostly-L2-served. o varies slowest within an
//    XCD so the temporal channel working set stays small.
__global__ __launch_bounds__(256) void lp_conv_bt_kernel(
    const float* __restrict__ x,       // (B, C_IN, H, W)
    const float* __restrict__ weights, // (C_OUT, CONN)
    const float* __restrict__ bias,    // (C_OUT)
    const int*   __restrict__ conn,    // (C_OUT, CONN)
    float*       __restrict__ out)     // (B, C_OUT, H, W)
{
    const int bid = blockIdx.x;        // 8192 = 8 xcd * 4 b * 128 o * 2 half
    const int xcd = bid & 7;
    const int n   = bid >> 3;          // [0,1024)
    const int b   = (xcd << 2) | (n & 3);
    const int m   = n >> 2;            // [0,256)
    const int ihalf = m & 1;
    const int o     = m >> 1;

    const int tid  = threadIdx.x;
    const int lane = tid & 63;
    int i0 = ihalf * 32 + (tid >> 6) * 8;
    i0 = __builtin_amdgcn_readfirstlane(i0);   // wave-uniform -> SALU addressing

    float acc[8];
#pragma unroll
    for (int i = 0; i < 8; ++i) acc[i] = 0.f;

#pragma unroll
    for (int k = 0; k < CONN; ++k) {
        const int   ci = conn[o * CONN + k];   // uniform -> s_load
        const float wk = weights[o * CONN + k];
        int c   = ci / 9;
        int rem = ci - c * 9;
        int di  = rem / 3;
        int dj  = rem - di * 3;

        // per-lane column (only per-lane VALU for this k): clamp(j + dj - 1)
        int col = lane + dj - 1;
        col = min(max(col, 0), WW - 1);

        const float* base = x + (((size_t)b * C_IN + c) << 12);  // channel base

#pragma unroll
        for (int i = 0; i < 8; ++i) {
            int hh = i0 + i + di - 1;          // wave-uniform row
            hh = min(max(hh, 0), HH - 1);
            float v = base[(hh << 6) + col];
            acc[i] = fmaxf(acc[i], fabsf(wk - v));
        }
    }

    const float bo = bias[o];
    float* po = out + (((size_t)(b * C_OUT + o) * HH + i0) << 6) + lane;
#pragma unroll
    for (int i = 0; i < 8; ++i)
        po[i << 6] = acc[i] + bo;
}

extern "C" void kernel_launch(void* const* d_in, const int* in_sizes, int n_in,
                              void* d_out, int out_size, void* d_ws, size_t ws_size,
                              hipStream_t stream) {
    const float* x       = (const float*)d_in[0];
    const float* weights = (const float*)d_in[1];
    const float* bias    = (const float*)d_in[2];
    const int*   conn    = (const int*)d_in[3];
    float*       out     = (float*)d_out;

    int grid = BB * C_OUT * 2;   // 8192 blocks of 256 threads
    lp_conv_bt_kernel<<<grid, 256, 0, stream>>>(x, weights, bias, conn, out);
}

// Round 7
// 105.577 us; speedup vs baseline: 1.0772x; 1.0140x over previous
//
#include <hip/hip_runtime.h>

// Problem constants (from reference)
#define BB     32
#define C_IN   64
#define HH     64
#define WW     64
#define C_OUT  128
#define CONN   4     // 1 << TREE_DEPTH
// PADDING=2 -> pad_l = pad_r = 1, "edge" mode -> clamp coords to [0, 63]

// Round-2 structure + CORRECTED XCD swizzle (b slowest within an XCD).
//  - lane (0..63) = output column j -> fully coalesced 256 B loads/stores
//  - each thread: 8 consecutive rows; block = 4 waves = 32 rows (ihalf picks half)
//  - o block-uniform -> conn/weights/bias scalarize; i0 wave-uniform -> SALU rows
//  - XCD swizzle: hw round-robins blockIdx across 8 XCDs (xcd = bid & 7).
//    XCD x receives n = bid>>3 = 0..1023 in order. Decode so that:
//      b     = xcd*4 + (n >> 8)   <- b changes only every 256 blocks: at any
//                                    instant one XCD works on ONE batch (2 MB
//                                    of x, fits the 4 MB per-XCD L2)
//      o     = (n >> 1) & 127     <- consecutive blocks share o (both halves):
//      ihalf = n & 1                 same 4 channels stay hot
//    Previous (neutral) version had b = fastest index -> 8 MB/XCD working set,
//    same thrash as default mapping. This is the actual test of the theory.
__global__ __launch_bounds__(256) void lp_conv_bt_kernel(
    const float* __restrict__ x,       // (B, C_IN, H, W)
    const float* __restrict__ weights, // (C_OUT, CONN)
    const float* __restrict__ bias,    // (C_OUT)
    const int*   __restrict__ conn,    // (C_OUT, CONN)
    float*       __restrict__ out)     // (B, C_OUT, H, W)
{
    const int bid = blockIdx.x;        // 8192 = 8 xcd * 4 b * 128 o * 2 half
    const int xcd = bid & 7;
    const int n   = bid >> 3;          // [0,1024), sequential per XCD
    const int b   = (xcd << 2) | (n >> 8);
    const int o   = (n >> 1) & (C_OUT - 1);
    const int ihalf = n & 1;

    const int tid  = threadIdx.x;
    const int lane = tid & 63;
    int i0 = ihalf * 32 + (tid >> 6) * 8;
    i0 = __builtin_amdgcn_readfirstlane(i0);   // wave-uniform -> SALU addressing

    float acc[8];
#pragma unroll
    for (int i = 0; i < 8; ++i) acc[i] = 0.f;

#pragma unroll
    for (int k = 0; k < CONN; ++k) {
        const int   ci = conn[o * CONN + k];   // uniform -> s_load
        const float wk = weights[o * CONN + k];
        int c   = ci / 9;
        int rem = ci - c * 9;
        int di  = rem / 3;
        int dj  = rem - di * 3;

        // per-lane column (only per-lane VALU for this k): clamp(j + dj - 1)
        int col = lane + dj - 1;
        col = min(max(col, 0), WW - 1);

        const float* base = x + (((size_t)b * C_IN + c) << 12);  // channel base

#pragma unroll
        for (int i = 0; i < 8; ++i) {
            int hh = i0 + i + di - 1;          // wave-uniform row
            hh = min(max(hh, 0), HH - 1);
            float v = base[(hh << 6) + col];
            acc[i] = fmaxf(acc[i], fabsf(wk - v));
        }
    }

    const float bo = bias[o];
    float* po = out + (((size_t)(b * C_OUT + o) * HH + i0) << 6) + lane;
#pragma unroll
    for (int i = 0; i < 8; ++i)
        po[i << 6] = acc[i] + bo;
}

extern "C" void kernel_launch(void* const* d_in, const int* in_sizes, int n_in,
                              void* d_out, int out_size, void* d_ws, size_t ws_size,
                              hipStream_t stream) {
    const float* x       = (const float*)d_in[0];
    const float* weights = (const float*)d_in[1];
    const float* bias    = (const float*)d_in[2];
    const int*   conn    = (const int*)d_in[3];
    float*       out     = (float*)d_out;

    int grid = BB * C_OUT * 2;   // 8192 blocks of 256 threads
    lp_conv_bt_kernel<<<grid, 256, 0, stream>>>(x, weights, bias, conn, out);
}

// Round 8
// 98.705 us; speedup vs baseline: 1.1522x; 1.0696x over previous
//
#include <hip/hip_runtime.h>

// Problem constants (from reference)
#define BB     32
#define C_IN   64
#define HH     64
#define WW     64
#define C_OUT  128
#define CONN   4     // 1 << TREE_DEPTH
// PADDING=2 -> pad_l = pad_r = 1, "edge" mode -> clamp coords to [0, 63]

// Round-7 structure (corrected XCD swizzle, b slowest per XCD) + NONTEMPORAL
// output stores.
//  Theory: the 65.5 MB output stream write-allocates in the 4 MB per-XCD L2,
//  continuously evicting x (2 MB/batch) -- which is why both swizzle variants
//  were neutral: the read working set was localized but never STAYED resident.
//  NT stores keep the output stream out of L2, so the 234 MB of x re-reads
//  (8x reuse across o) turn into L2 hits instead of Infinity-Cache traffic.
//  - lane (0..63) = output column j -> fully coalesced 256 B loads/stores
//  - each thread: 8 consecutive rows; block = 4 waves = 32 rows
//  - o block-uniform -> conn/weights/bias scalarize; i0 wave-uniform -> SALU
__global__ __launch_bounds__(256) void lp_conv_bt_kernel(
    const float* __restrict__ x,       // (B, C_IN, H, W)
    const float* __restrict__ weights, // (C_OUT, CONN)
    const float* __restrict__ bias,    // (C_OUT)
    const int*   __restrict__ conn,    // (C_OUT, CONN)
    float*       __restrict__ out)     // (B, C_OUT, H, W)
{
    const int bid = blockIdx.x;        // 8192 = 8 xcd * 4 b * 128 o * 2 half
    const int xcd = bid & 7;
    const int n   = bid >> 3;          // [0,1024), sequential per XCD
    const int b   = (xcd << 2) | (n >> 8);
    const int o   = (n >> 1) & (C_OUT - 1);
    const int ihalf = n & 1;

    const int tid  = threadIdx.x;
    const int lane = tid & 63;
    int i0 = ihalf * 32 + (tid >> 6) * 8;
    i0 = __builtin_amdgcn_readfirstlane(i0);   // wave-uniform -> SALU addressing

    float acc[8];
#pragma unroll
    for (int i = 0; i < 8; ++i) acc[i] = 0.f;

#pragma unroll
    for (int k = 0; k < CONN; ++k) {
        const int   ci = conn[o * CONN + k];   // uniform -> s_load
        const float wk = weights[o * CONN + k];
        int c   = ci / 9;
        int rem = ci - c * 9;
        int di  = rem / 3;
        int dj  = rem - di * 3;

        // per-lane column (only per-lane VALU for this k): clamp(j + dj - 1)
        int col = lane + dj - 1;
        col = min(max(col, 0), WW - 1);

        const float* base = x + (((size_t)b * C_IN + c) << 12);  // channel base

#pragma unroll
        for (int i = 0; i < 8; ++i) {
            int hh = i0 + i + di - 1;          // wave-uniform row
            hh = min(max(hh, 0), HH - 1);
            float v = base[(hh << 6) + col];
            acc[i] = fmaxf(acc[i], fabsf(wk - v));
        }
    }

    const float bo = bias[o];
    float* po = out + (((size_t)(b * C_OUT + o) * HH + i0) << 6) + lane;
#pragma unroll
    for (int i = 0; i < 8; ++i)
        __builtin_nontemporal_store(acc[i] + bo, po + (i << 6));
}

extern "C" void kernel_launch(void* const* d_in, const int* in_sizes, int n_in,
                              void* d_out, int out_size, void* d_ws, size_t ws_size,
                              hipStream_t stream) {
    const float* x       = (const float*)d_in[0];
    const float* weights = (const float*)d_in[1];
    const float* bias    = (const float*)d_in[2];
    const int*   conn    = (const int*)d_in[3];
    float*       out     = (float*)d_out;

    int grid = BB * C_OUT * 2;   // 8192 blocks of 256 threads
    lp_conv_bt_kernel<<<grid, 256, 0, stream>>>(x, weights, bias, conn, out);
}